// Round 9
// baseline (736.377 us; speedup 1.0000x reference)
//
#include <hip/hip_runtime.h>
#include <cstdint>
#include <cstddef>

// T=1024 tokens, H=2048, F=1024, E=8, K=2
#define T_TOK 1024
#define H_DIM 2048
#define F_DIM 1024
#define E_EXP 8
#define BM 64
#define BK 64
#define MAX_TILES 40
#define ROWCAP 2560

// ---- workspace layout ----
#define I_NTILES 25     // int
#define I_TILE_E 32     // int[48]
#define I_TILE_R0 80    // int[48]
#define I_ROWTOK 4224   // int[2560]
#define I_ROWW   6784   // float[2560]
#define B_XB     37888                          // bf16 x [1024][2048]      (4 MB)
#define B_AWS    (B_XB + T_TOK*H_DIM*2)         // bf16 act [2560][1024]    (5 MB)
#define B_W1P    (B_AWS + ROWCAP*F_DIM*2)       // bf16 w1p pack8 (32 MB)
#define B_W3P    (B_W1P + E_EXP*F_DIM*H_DIM*2)  // bf16 w3p pack8 (32 MB)
#define B_W2P    (B_W3P + E_EXP*F_DIM*H_DIM*2)  // bf16 w2p pack8 (32 MB)

typedef __bf16 bf16x8 __attribute__((ext_vector_type(8)));
typedef float  f32x4  __attribute__((ext_vector_type(4)));

#define MFMA(a,b,c) __builtin_amdgcn_mfma_f32_16x16x32_bf16(a,b,c,0,0,0)
#define VM_DRAIN() asm volatile("s_waitcnt vmcnt(0)" ::: "memory")

__device__ __forceinline__ void gload16(const void* g, void* l) {
  __builtin_amdgcn_global_load_lds(
      (const __attribute__((address_space(1))) void*)g,
      (__attribute__((address_space(3))) void*)l, 16, 0, 0);
}

// ---------------- fused router + scan + assign ----------------
__global__ __launch_bounds__(1024) void k_route(const float* __restrict__ logits,
                                                int* __restrict__ ws_i) {
  __shared__ int cnt[E_EXP], cur[E_EXP], offs_s[E_EXP];
  const int t = threadIdx.x;
  float* ws_f = (float*)ws_i;
  if (t < E_EXP) { cnt[t] = 0; cur[t] = 0; }
  __syncthreads();
  float l[E_EXP];
#pragma unroll
  for (int e = 0; e < E_EXP; ++e) l[e] = logits[t * E_EXP + e];
  int b0 = 0; float v0 = l[0];
#pragma unroll
  for (int e = 1; e < E_EXP; ++e) if (l[e] > v0) { v0 = l[e]; b0 = e; }
  int b1 = -1; float v1 = -3.4e38f;
#pragma unroll
  for (int e = 0; e < E_EXP; ++e) if (e != b0 && l[e] > v1) { v1 = l[e]; b1 = e; }
  float w0 = 1.f / (1.f + __expf(v1 - v0));
  float w1 = 1.f - w0;
  atomicAdd(&cnt[b0], 1);
  atomicAdd(&cnt[b1], 1);
  __syncthreads();
  if (t == 0) {
    int off = 0, nt = 0;
    for (int e = 0; e < E_EXP; ++e) {
      offs_s[e] = off;
      int ntile = (cnt[e] + BM - 1) / BM;
      for (int i = 0; i < ntile; ++i) {
        ws_i[I_TILE_E + nt] = e;
        ws_i[I_TILE_R0 + nt] = off + i * BM;
        ++nt;
      }
      off += ntile * BM;
    }
    ws_i[I_NTILES] = nt;
  }
  for (int i = t; i < ROWCAP; i += 1024) {
    ws_i[I_ROWTOK + i] = -1;
    ws_f[I_ROWW + i] = 0.f;            // no poison reads anywhere
  }
  __syncthreads();
  {
    int p = atomicAdd(&cur[b0], 1);
    int s = offs_s[b0] + p;
    ws_i[I_ROWTOK + s] = t;
    ws_f[I_ROWW + s] = w0;
  }
  {
    int p = atomicAdd(&cur[b1], 1);
    int s = offs_s[b1] + p;
    ws_i[I_ROWTOK + s] = t;
    ws_f[I_ROWW + s] = w1;
  }
  __threadfence();                      // agent-scope release for consumers
}

// ---------------- x fp32 -> bf16 ----------------
__global__ __launch_bounds__(256) void k_cvt(const float* __restrict__ x,
                                             __bf16* __restrict__ xb) {
  long i = (long)(blockIdx.x * 256 + threadIdx.x) * 8;
  float4 a = *(const float4*)(x + i);
  float4 b = *(const float4*)(x + i + 4);
  bf16x8 v;
  v[0] = (__bf16)a.x; v[1] = (__bf16)a.y; v[2] = (__bf16)a.z; v[3] = (__bf16)a.w;
  v[4] = (__bf16)b.x; v[5] = (__bf16)b.y; v[6] = (__bf16)b.z; v[7] = (__bf16)b.w;
  *(bf16x8*)(xb + i) = v;
  __threadfence();
}

// ---------------- pack8 convert: fp32 [R][C] -> bf16 [R/8][C][8], LDS-free ----------------
__global__ __launch_bounds__(256) void k_cvtW(const float* __restrict__ w1,
                                              const float* __restrict__ w3,
                                              const float* __restrict__ w2,
                                              __bf16* __restrict__ w1p,
                                              __bf16* __restrict__ w3p,
                                              __bf16* __restrict__ w2p) {
  const int NT = 24 * 65536;
  const int step = gridDim.x * 256;
  for (int idx = blockIdx.x * 256 + threadIdx.x; idx < NT; idx += step) {
    const int z = idx >> 16;
    const int r = idx & 65535;
    const float* src; __bf16* dst; int C, kp, nq;
    if (z < 8) {
      src = w1 + (size_t)z * H_DIM * F_DIM; dst = w1p + (size_t)z * H_DIM * F_DIM;
      C = F_DIM; nq = r & 255; kp = r >> 8;
    } else if (z < 16) {
      src = w3 + (size_t)(z - 8) * H_DIM * F_DIM; dst = w3p + (size_t)(z - 8) * H_DIM * F_DIM;
      C = F_DIM; nq = r & 255; kp = r >> 8;
    } else {
      src = w2 + (size_t)(z - 16) * F_DIM * H_DIM; dst = w2p + (size_t)(z - 16) * F_DIM * H_DIM;
      C = H_DIM; nq = r & 511; kp = r >> 9;
    }
    const float* s = src + (size_t)(kp * 8) * C + nq * 4;
    f32x4 q0 = *(const f32x4*)(s + 0 * (size_t)C);
    f32x4 q1 = *(const f32x4*)(s + 1 * (size_t)C);
    f32x4 q2 = *(const f32x4*)(s + 2 * (size_t)C);
    f32x4 q3 = *(const f32x4*)(s + 3 * (size_t)C);
    f32x4 q4 = *(const f32x4*)(s + 4 * (size_t)C);
    f32x4 q5 = *(const f32x4*)(s + 5 * (size_t)C);
    f32x4 q6 = *(const f32x4*)(s + 6 * (size_t)C);
    f32x4 q7 = *(const f32x4*)(s + 7 * (size_t)C);
    __bf16* d = dst + ((size_t)kp * C + nq * 4) * 8;
#pragma unroll
    for (int u = 0; u < 4; ++u) {
      bf16x8 v;
      v[0] = (__bf16)q0[u]; v[1] = (__bf16)q1[u];
      v[2] = (__bf16)q2[u]; v[3] = (__bf16)q3[u];
      v[4] = (__bf16)q4[u]; v[5] = (__bf16)q5[u];
      v[6] = (__bf16)q6[u]; v[7] = (__bf16)q7[u];
      *(bf16x8*)(d + u * 8) = v;
    }
  }
  __threadfence();                      // release converted weights to all XCDs
}

// ---------------- GEMM1: a = silu(x·w1)*(x·w3) -> aws bf16 ----------------
__global__ __launch_bounds__(256) void k_gemm1(const __bf16* __restrict__ xb,
                                               const __bf16* __restrict__ w1p,
                                               const __bf16* __restrict__ w3p,
                                               const int* __restrict__ ws_i,
                                               __bf16* __restrict__ aws) {
  __shared__ __bf16 sm[2][3 * 4096];   // per buf: As | B1 | B3, 64x64 bf16 linear
  __shared__ int s_tok[BM];
  const int p = blockIdx.x;                   // 640 = 8 XCD * 80
  const int lg = (p & 7) * 80 + (p >> 3);
  const int tile = lg % MAX_TILES;
  const int n0 = (lg / MAX_TILES) * 64;
  if (tile >= ws_i[I_NTILES]) return;
  const int e  = ws_i[I_TILE_E + tile];
  const int r0 = ws_i[I_TILE_R0 + tile];
  const int tid = threadIdx.x, lane = tid & 63, wid = tid >> 6;
  const int wm = wid >> 1, wn = wid & 1;
  const int l15 = lane & 15, l4 = lane >> 4;
  if (tid < BM) {
    int tk = ws_i[I_ROWTOK + r0 + tid];
    s_tok[tid] = tk < 0 ? 0 : tk;     // padded rows compute garbage, never scattered
  }
  __syncthreads();
  // staging: lane -> row rj, octet slot lane&7; source octet XOR-pre-swizzled (rule 21)
  const int rj0 = wid * 16 + (lane >> 3);
  const int rj1 = rj0 + 8;
  const int s8 = (lane & 7) ^ (lane >> 3);
  const __bf16* gA0 = xb + (size_t)s_tok[rj0] * H_DIM + s8 * 8;
  const __bf16* gA1 = xb + (size_t)s_tok[rj1] * H_DIM + s8 * 8;
  // pack8: elem(e,k,n) at e*H*F + ((k>>3)*F + n)*8 + (k&7)
  const __bf16* w1e = w1p + (size_t)e * H_DIM * F_DIM;
  const __bf16* w3e = w3p + (size_t)e * H_DIM * F_DIM;
  const __bf16* gB1_0 = w1e + ((size_t)s8 * F_DIM + n0 + rj0) * 8;
  const __bf16* gB1_1 = w1e + ((size_t)s8 * F_DIM + n0 + rj1) * 8;
  const __bf16* gB3_0 = w3e + ((size_t)s8 * F_DIM + n0 + rj0) * 8;
  const __bf16* gB3_1 = w3e + ((size_t)s8 * F_DIM + n0 + rj1) * 8;
  const int c0 = wid * 2 * 512, c1 = c0 + 512;

  auto STAGE = [&](int b, int t) {
    __bf16* As = &sm[b][0];
    __bf16* B1 = &sm[b][4096];
    __bf16* B3 = &sm[b][8192];
    const size_t ka = (size_t)t * BK;
    const size_t kb = (size_t)t * BK * F_DIM;
    gload16(gA0 + ka,   As + c0);
    gload16(gA1 + ka,   As + c1);
    gload16(gB1_0 + kb, B1 + c0);
    gload16(gB1_1 + kb, B1 + c1);
    gload16(gB3_0 + kb, B3 + c0);
    gload16(gB3_1 + kb, B3 + c1);
  };

  f32x4 accg[2][2] = {}; f32x4 accu[2][2] = {};
  auto COMPUTE = [&](int b) {
    const __bf16* As = &sm[b][0];
    const __bf16* B1 = &sm[b][4096];
    const __bf16* B3 = &sm[b][8192];
    __builtin_amdgcn_s_setprio(1);
#pragma unroll
    for (int kk = 0; kk < 2; ++kk) {
      const int sx = ((kk * 4 + l4) ^ (lane & 7)) << 3;
      const int ra0 = wm * 32 + l15, ra1 = ra0 + 16;
      const int rb0 = wn * 32 + l15, rb1 = rb0 + 16;
      bf16x8 a0  = *(const bf16x8*)&As[ra0 * 64 + sx];
      bf16x8 a1  = *(const bf16x8*)&As[ra1 * 64 + sx];
      bf16x8 b10 = *(const bf16x8*)&B1[rb0 * 64 + sx];
      bf16x8 b11 = *(const bf16x8*)&B1[rb1 * 64 + sx];
      bf16x8 b30 = *(const bf16x8*)&B3[rb0 * 64 + sx];
      bf16x8 b31 = *(const bf16x8*)&B3[rb1 * 64 + sx];
      accg[0][0] = MFMA(a0, b10, accg[0][0]);
      accg[0][1] = MFMA(a0, b11, accg[0][1]);
      accg[1][0] = MFMA(a1, b10, accg[1][0]);
      accg[1][1] = MFMA(a1, b11, accg[1][1]);
      accu[0][0] = MFMA(a0, b30, accu[0][0]);
      accu[0][1] = MFMA(a0, b31, accu[0][1]);
      accu[1][0] = MFMA(a1, b30, accu[1][0]);
      accu[1][1] = MFMA(a1, b31, accu[1][1]);
    }
    __builtin_amdgcn_s_setprio(0);
  };

  STAGE(0, 0);
  VM_DRAIN();                   // explicit: all gload-LDS writes landed
  __syncthreads();
  int curb = 0;
  for (int t = 0; t < H_DIM / BK; ++t) {
    if (t + 1 < H_DIM / BK) STAGE(curb ^ 1, t + 1);
    COMPUTE(curb);
    VM_DRAIN();                 // drain this wave's staged loads before barrier
    __syncthreads();
    curb ^= 1;
  }
#pragma unroll
  for (int fm = 0; fm < 2; ++fm)
#pragma unroll
    for (int fn = 0; fn < 2; ++fn)
#pragma unroll
      for (int r = 0; r < 4; ++r) {
        float g = accg[fm][fn][r], u = accu[fm][fn][r];
        float a = g / (1.f + __expf(-g)) * u;
        int row = r0 + wm * 32 + fm * 16 + l4 * 4 + r;
        int col = n0 + wn * 32 + fn * 16 + l15;
        aws[(size_t)row * F_DIM + col] = (__bf16)a;
      }
  __threadfence();              // release activations to gemm2 on all XCDs
}

// ---------------- GEMM2: y = a·w2, weighted atomic scatter ----------------
__global__ __launch_bounds__(256) void k_gemm2(const __bf16* __restrict__ aws,
                                               const __bf16* __restrict__ w2p,
                                               const int* __restrict__ ws_i,
                                               float* __restrict__ out) {
  __shared__ __bf16 sm[2][2 * 4096];   // per buf: As | Bs
  __shared__ int s_tok[BM];
  __shared__ float s_w[BM];
  const int p = blockIdx.x;                 // 1280 = 8 XCD * 160
  const int lg = (p & 7) * 160 + (p >> 3);
  const int tile = lg % MAX_TILES;
  const int h0 = (lg / MAX_TILES) * 64;
  if (tile >= ws_i[I_NTILES]) return;
  const int e  = ws_i[I_TILE_E + tile];
  const int r0 = ws_i[I_TILE_R0 + tile];
  const int tid = threadIdx.x, lane = tid & 63, wid = tid >> 6;
  const int wm = wid >> 1, wn = wid & 1;
  const int l15 = lane & 15, l4 = lane >> 4;
  const float* ws_f = (const float*)ws_i;
  if (tid < BM) {
    s_tok[tid] = ws_i[I_ROWTOK + r0 + tid];
    s_w[tid]   = ws_f[I_ROWW + r0 + tid];
  }
  __syncthreads();
  const int rj0 = wid * 16 + (lane >> 3);
  const int rj1 = rj0 + 8;
  const int s8 = (lane & 7) ^ (lane >> 3);
  const __bf16* gA0 = aws + (size_t)(r0 + rj0) * F_DIM + s8 * 8;
  const __bf16* gA1 = aws + (size_t)(r0 + rj1) * F_DIM + s8 * 8;
  // pack8: elem(e,k,h) at e*F*H + ((k>>3)*H + h)*8 + (k&7)
  const __bf16* w2e = w2p + (size_t)e * F_DIM * H_DIM;
  const __bf16* gB0 = w2e + ((size_t)s8 * H_DIM + h0 + rj0) * 8;
  const __bf16* gB1 = w2e + ((size_t)s8 * H_DIM + h0 + rj1) * 8;
  const int c0 = wid * 2 * 512, c1 = c0 + 512;

  auto STAGE = [&](int b, int t) {
    __bf16* As = &sm[b][0];
    __bf16* Bs = &sm[b][4096];
    const size_t ka = (size_t)t * BK;
    const size_t kb = (size_t)t * BK * H_DIM;
    gload16(gA0 + ka, As + c0);
    gload16(gA1 + ka, As + c1);
    gload16(gB0 + kb, Bs + c0);
    gload16(gB1 + kb, Bs + c1);
  };

  f32x4 acc[2][2] = {};
  auto COMPUTE = [&](int b) {
    const __bf16* As = &sm[b][0];
    const __bf16* Bs = &sm[b][4096];
    __builtin_amdgcn_s_setprio(1);
#pragma unroll
    for (int kk = 0; kk < 2; ++kk) {
      const int sx = ((kk * 4 + l4) ^ (lane & 7)) << 3;
      const int ra0 = wm * 32 + l15, ra1 = ra0 + 16;
      const int rb0 = wn * 32 + l15, rb1 = rb0 + 16;
      bf16x8 a0 = *(const bf16x8*)&As[ra0 * 64 + sx];
      bf16x8 a1 = *(const bf16x8*)&As[ra1 * 64 + sx];
      bf16x8 b0 = *(const bf16x8*)&Bs[rb0 * 64 + sx];
      bf16x8 b1 = *(const bf16x8*)&Bs[rb1 * 64 + sx];
      acc[0][0] = MFMA(a0, b0, acc[0][0]);
      acc[0][1] = MFMA(a0, b1, acc[0][1]);
      acc[1][0] = MFMA(a1, b0, acc[1][0]);
      acc[1][1] = MFMA(a1, b1, acc[1][1]);
    }
    __builtin_amdgcn_s_setprio(0);
  };

  STAGE(0, 0);
  VM_DRAIN();
  __syncthreads();
  int curb = 0;
  for (int t = 0; t < F_DIM / BK; ++t) {
    if (t + 1 < F_DIM / BK) STAGE(curb ^ 1, t + 1);
    COMPUTE(curb);
    VM_DRAIN();
    __syncthreads();
    curb ^= 1;
  }
  // exactly 2 atomic adds per output element (K=2): order-independent (a+b exact)
#pragma unroll
  for (int fm = 0; fm < 2; ++fm)
#pragma unroll
    for (int fn = 0; fn < 2; ++fn)
#pragma unroll
      for (int r = 0; r < 4; ++r) {
        int lrow = wm * 32 + fm * 16 + l4 * 4 + r;
        int t = s_tok[lrow];
        if (t >= 0) {
          float v = acc[fm][fn][r] * s_w[lrow];
          atomicAdd(out + (size_t)t * H_DIM + h0 + wn * 32 + fn * 16 + l15, v);
        }
      }
}

extern "C" void kernel_launch(void* const* d_in, const int* in_sizes, int n_in,
                              void* d_out, int out_size, void* d_ws, size_t ws_size,
                              hipStream_t stream) {
  (void)in_sizes; (void)n_in; (void)out_size; (void)ws_size;
  const float* x      = (const float*)d_in[0];
  const float* logits = (const float*)d_in[1];
  const float* w1     = (const float*)d_in[2];
  const float* w3     = (const float*)d_in[3];
  const float* w2     = (const float*)d_in[4];
  float* out = (float*)d_out;
  int* ws_i = (int*)d_ws;
  __bf16* xb  = (__bf16*)((char*)d_ws + B_XB);
  __bf16* aws = (__bf16*)((char*)d_ws + B_AWS);
  __bf16* w1p = (__bf16*)((char*)d_ws + B_W1P);
  __bf16* w3p = (__bf16*)((char*)d_ws + B_W3P);
  __bf16* w2p = (__bf16*)((char*)d_ws + B_W2P);

  hipMemsetAsync(d_out, 0, (size_t)T_TOK * H_DIM * sizeof(float), stream);
  k_route<<<1, 1024, 0, stream>>>(logits, ws_i);
  k_cvt<<<dim3(T_TOK * H_DIM / (256 * 8)), 256, 0, stream>>>(x, xb);
  k_cvtW<<<dim3(2048), 256, 0, stream>>>(w1, w3, w2, w1p, w3p, w2p);
  k_gemm1<<<dim3(MAX_TILES * (F_DIM / 64)), 256, 0, stream>>>(xb, w1p, w3p, ws_i, aws);
  k_gemm2<<<dim3(MAX_TILES * (H_DIM / 64)), 256, 0, stream>>>(aws, w2p, ws_i, out);
}

// Round 11
// 168.287 us; speedup vs baseline: 4.3757x; 4.3757x over previous
//
#include <hip/hip_runtime.h>
#include <cstdint>
#include <cstddef>

// T=1024 tokens, H=2048, F=1024, E=8, K=2
#define T_TOK 1024
#define H_DIM 2048
#define F_DIM 1024
#define E_EXP 8
#define BM 64
#define BK 64
#define MAX_TILES 40
#define ROWCAP 2560

// ---- workspace layout ----
#define I_NTILES 25     // int
#define I_TILE_E 32     // int[48]
#define I_TILE_R0 80    // int[48]
#define I_ROWTOK 4224   // int[2560]
#define I_ROWW   6784   // float[2560]
#define B_XB     37888                          // bf16 x [1024][2048]      (4 MB)
#define B_AWS    (B_XB + T_TOK*H_DIM*2)         // bf16 act [2560][1024]    (5 MB)
#define B_W1P    (B_AWS + ROWCAP*F_DIM*2)       // bf16 w1p pack8 (32 MB)
#define B_W3P    (B_W1P + E_EXP*F_DIM*H_DIM*2)  // bf16 w3p pack8 (32 MB)
#define B_W2P    (B_W3P + E_EXP*F_DIM*H_DIM*2)  // bf16 w2p pack8 (32 MB)

typedef __bf16 bf16x8 __attribute__((ext_vector_type(8)));
typedef float  f32x4  __attribute__((ext_vector_type(4)));

#define MFMA(a,b,c) __builtin_amdgcn_mfma_f32_16x16x32_bf16(a,b,c,0,0,0)
// Explicit drain before each pipeline barrier (m152-class dbuf hazard guard).
#define VM_DRAIN() asm volatile("s_waitcnt vmcnt(0)" ::: "memory")

__device__ __forceinline__ void gload16(const void* g, void* l) {
  __builtin_amdgcn_global_load_lds(
      (const __attribute__((address_space(1))) void*)g,
      (__attribute__((address_space(3))) void*)l, 16, 0, 0);
}

// ---------------- deterministic router: prefix-sum ranks (no atomic order dependence) ----------------
// All ws content is bitwise identical on every call -> stale-L2-line reads across
// graph replays are value-identical (this was r8/r10's post-timing divergence).
__global__ __launch_bounds__(1024) void k_route(const float* __restrict__ logits,
                                                int* __restrict__ ws_i) {
  __shared__ int wtot[16][E_EXP];     // per-wave expert counts
  __shared__ int woff[16][E_EXP];     // exclusive wave offsets
  __shared__ int offs_s[E_EXP];       // padded expert base rows
  const int t = threadIdx.x;
  const int lane = t & 63, wv = t >> 6;
  float* ws_f = (float*)ws_i;
  float l[E_EXP];
#pragma unroll
  for (int e = 0; e < E_EXP; ++e) l[e] = logits[t * E_EXP + e];
  int b0 = 0; float v0 = l[0];
#pragma unroll
  for (int e = 1; e < E_EXP; ++e) if (l[e] > v0) { v0 = l[e]; b0 = e; }
  int b1 = -1; float v1 = -3.4e38f;
#pragma unroll
  for (int e = 0; e < E_EXP; ++e) if (e != b0 && l[e] > v1) { v1 = l[e]; b1 = e; }
  float w0 = 1.f / (1.f + __expf(v1 - v0));
  float w1 = 1.f - w0;
  // 8 experts x 8-bit indicator pack (wave count <= 64 fits 8 bits; b0 != b1)
  unsigned long long inc = (1ull << (8 * b0)) | (1ull << (8 * b1));
  for (int d = 1; d < 64; d <<= 1) {
    unsigned long long n = __shfl_up(inc, (unsigned)d);
    if (lane >= d) inc += n;
  }
  if (lane == 63) {
#pragma unroll
    for (int e = 0; e < E_EXP; ++e) wtot[wv][e] = (int)((inc >> (8 * e)) & 255);
  }
  for (int i = t; i < ROWCAP; i += 1024) {
    ws_i[I_ROWTOK + i] = -1;
    ws_f[I_ROWW + i] = 0.f;           // padded rows: no poison anywhere
  }
  __syncthreads();
  if (t == 0) {
    int run[E_EXP] = {};
    for (int w = 0; w < 16; ++w)
#pragma unroll
      for (int e = 0; e < E_EXP; ++e) { woff[w][e] = run[e]; run[e] += wtot[w][e]; }
    int off = 0, ntl = 0;
    for (int e = 0; e < E_EXP; ++e) {
      offs_s[e] = off;
      int ntile = (run[e] + BM - 1) / BM;
      for (int i = 0; i < ntile; ++i) {
        ws_i[I_TILE_E + ntl] = e;
        ws_i[I_TILE_R0 + ntl] = off + i * BM;
        ++ntl;
      }
      off += ntile * BM;
    }
    ws_i[I_NTILES] = ntl;
  }
  __syncthreads();
  // exclusive rank = inclusive scan - own indicator; rows sorted by token id (deterministic)
  const int rnk0 = woff[wv][b0] + (int)((inc >> (8 * b0)) & 255) - 1;
  const int rnk1 = woff[wv][b1] + (int)((inc >> (8 * b1)) & 255) - 1;
  const int s0 = offs_s[b0] + rnk0;
  const int s1 = offs_s[b1] + rnk1;
  ws_i[I_ROWTOK + s0] = t;  ws_f[I_ROWW + s0] = w0;
  ws_i[I_ROWTOK + s1] = t;  ws_f[I_ROWW + s1] = w1;
}

// ---------------- x fp32 -> bf16 ----------------
__global__ __launch_bounds__(256) void k_cvt(const float* __restrict__ x,
                                             __bf16* __restrict__ xb) {
  long i = (long)(blockIdx.x * 256 + threadIdx.x) * 8;
  float4 a = *(const float4*)(x + i);
  float4 b = *(const float4*)(x + i + 4);
  bf16x8 v;
  v[0] = (__bf16)a.x; v[1] = (__bf16)a.y; v[2] = (__bf16)a.z; v[3] = (__bf16)a.w;
  v[4] = (__bf16)b.x; v[5] = (__bf16)b.y; v[6] = (__bf16)b.z; v[7] = (__bf16)b.w;
  *(bf16x8*)(xb + i) = v;
}

// ---------------- pack8 convert: fp32 [R][C] -> bf16 [R/8][C][8], LDS-free ----------------
__global__ __launch_bounds__(256) void k_cvtW(const float* __restrict__ w1,
                                              const float* __restrict__ w3,
                                              const float* __restrict__ w2,
                                              __bf16* __restrict__ w1p,
                                              __bf16* __restrict__ w3p,
                                              __bf16* __restrict__ w2p) {
  const int NT = 24 * 65536;
  const int step = gridDim.x * 256;
  for (int idx = blockIdx.x * 256 + threadIdx.x; idx < NT; idx += step) {
    const int z = idx >> 16;
    const int r = idx & 65535;
    const float* src; __bf16* dst; int C, kp, nq;
    if (z < 8) {
      src = w1 + (size_t)z * H_DIM * F_DIM; dst = w1p + (size_t)z * H_DIM * F_DIM;
      C = F_DIM; nq = r & 255; kp = r >> 8;
    } else if (z < 16) {
      src = w3 + (size_t)(z - 8) * H_DIM * F_DIM; dst = w3p + (size_t)(z - 8) * H_DIM * F_DIM;
      C = F_DIM; nq = r & 255; kp = r >> 8;
    } else {
      src = w2 + (size_t)(z - 16) * F_DIM * H_DIM; dst = w2p + (size_t)(z - 16) * F_DIM * H_DIM;
      C = H_DIM; nq = r & 511; kp = r >> 9;
    }
    const float* s = src + (size_t)(kp * 8) * C + nq * 4;
    f32x4 q0 = *(const f32x4*)(s + 0 * (size_t)C);
    f32x4 q1 = *(const f32x4*)(s + 1 * (size_t)C);
    f32x4 q2 = *(const f32x4*)(s + 2 * (size_t)C);
    f32x4 q3 = *(const f32x4*)(s + 3 * (size_t)C);
    f32x4 q4 = *(const f32x4*)(s + 4 * (size_t)C);
    f32x4 q5 = *(const f32x4*)(s + 5 * (size_t)C);
    f32x4 q6 = *(const f32x4*)(s + 6 * (size_t)C);
    f32x4 q7 = *(const f32x4*)(s + 7 * (size_t)C);
    __bf16* d = dst + ((size_t)kp * C + nq * 4) * 8;
#pragma unroll
    for (int u = 0; u < 4; ++u) {
      bf16x8 v;
      v[0] = (__bf16)q0[u]; v[1] = (__bf16)q1[u];
      v[2] = (__bf16)q2[u]; v[3] = (__bf16)q3[u];
      v[4] = (__bf16)q4[u]; v[5] = (__bf16)q5[u];
      v[6] = (__bf16)q6[u]; v[7] = (__bf16)q7[u];
      *(bf16x8*)(d + u * 8) = v;
    }
  }
}

// ---------------- GEMM1: a = silu(x·w1)*(x·w3) -> aws bf16 ----------------
__global__ __launch_bounds__(256) void k_gemm1(const __bf16* __restrict__ xb,
                                               const __bf16* __restrict__ w1p,
                                               const __bf16* __restrict__ w3p,
                                               const int* __restrict__ ws_i,
                                               __bf16* __restrict__ aws) {
  __shared__ __bf16 sm[2][3 * 4096];   // per buf: As | B1 | B3, 64x64 bf16 linear
  __shared__ int s_tok[BM];
  const int p = blockIdx.x;                   // 640 = 8 XCD * 80
  const int lg = (p & 7) * 80 + (p >> 3);
  const int tile = lg % MAX_TILES;
  const int n0 = (lg / MAX_TILES) * 64;
  if (tile >= ws_i[I_NTILES]) return;
  const int e  = ws_i[I_TILE_E + tile];
  const int r0 = ws_i[I_TILE_R0 + tile];
  const int tid = threadIdx.x, lane = tid & 63, wid = tid >> 6;
  const int wm = wid >> 1, wn = wid & 1;
  const int l15 = lane & 15, l4 = lane >> 4;
  if (tid < BM) {
    int tk = ws_i[I_ROWTOK + r0 + tid];
    s_tok[tid] = tk < 0 ? 0 : tk;     // padded rows compute garbage, never scattered
  }
  __syncthreads();
  // staging: lane -> row rj, octet slot lane&7; source octet XOR-pre-swizzled (rule 21)
  const int rj0 = wid * 16 + (lane >> 3);
  const int rj1 = rj0 + 8;
  const int s8 = (lane & 7) ^ (lane >> 3);
  const __bf16* gA0 = xb + (size_t)s_tok[rj0] * H_DIM + s8 * 8;
  const __bf16* gA1 = xb + (size_t)s_tok[rj1] * H_DIM + s8 * 8;
  // pack8: elem(e,k,n) at e*H*F + ((k>>3)*F + n)*8 + (k&7)
  const __bf16* w1e = w1p + (size_t)e * H_DIM * F_DIM;
  const __bf16* w3e = w3p + (size_t)e * H_DIM * F_DIM;
  const __bf16* gB1_0 = w1e + ((size_t)s8 * F_DIM + n0 + rj0) * 8;
  const __bf16* gB1_1 = w1e + ((size_t)s8 * F_DIM + n0 + rj1) * 8;
  const __bf16* gB3_0 = w3e + ((size_t)s8 * F_DIM + n0 + rj0) * 8;
  const __bf16* gB3_1 = w3e + ((size_t)s8 * F_DIM + n0 + rj1) * 8;
  const int c0 = wid * 2 * 512, c1 = c0 + 512;

  auto STAGE = [&](int b, int t) {
    __bf16* As = &sm[b][0];
    __bf16* B1 = &sm[b][4096];
    __bf16* B3 = &sm[b][8192];
    const size_t ka = (size_t)t * BK;
    const size_t kb = (size_t)t * BK * F_DIM;
    gload16(gA0 + ka,   As + c0);
    gload16(gA1 + ka,   As + c1);
    gload16(gB1_0 + kb, B1 + c0);
    gload16(gB1_1 + kb, B1 + c1);
    gload16(gB3_0 + kb, B3 + c0);
    gload16(gB3_1 + kb, B3 + c1);
  };

  f32x4 accg[2][2] = {}; f32x4 accu[2][2] = {};
  auto COMPUTE = [&](int b) {
    const __bf16* As = &sm[b][0];
    const __bf16* B1 = &sm[b][4096];
    const __bf16* B3 = &sm[b][8192];
    __builtin_amdgcn_s_setprio(1);
#pragma unroll
    for (int kk = 0; kk < 2; ++kk) {
      const int sx = ((kk * 4 + l4) ^ (lane & 7)) << 3;
      const int ra0 = wm * 32 + l15, ra1 = ra0 + 16;
      const int rb0 = wn * 32 + l15, rb1 = rb0 + 16;
      bf16x8 a0  = *(const bf16x8*)&As[ra0 * 64 + sx];
      bf16x8 a1  = *(const bf16x8*)&As[ra1 * 64 + sx];
      bf16x8 b10 = *(const bf16x8*)&B1[rb0 * 64 + sx];
      bf16x8 b11 = *(const bf16x8*)&B1[rb1 * 64 + sx];
      bf16x8 b30 = *(const bf16x8*)&B3[rb0 * 64 + sx];
      bf16x8 b31 = *(const bf16x8*)&B3[rb1 * 64 + sx];
      accg[0][0] = MFMA(a0, b10, accg[0][0]);
      accg[0][1] = MFMA(a0, b11, accg[0][1]);
      accg[1][0] = MFMA(a1, b10, accg[1][0]);
      accg[1][1] = MFMA(a1, b11, accg[1][1]);
      accu[0][0] = MFMA(a0, b30, accu[0][0]);
      accu[0][1] = MFMA(a0, b31, accu[0][1]);
      accu[1][0] = MFMA(a1, b30, accu[1][0]);
      accu[1][1] = MFMA(a1, b31, accu[1][1]);
    }
    __builtin_amdgcn_s_setprio(0);
  };

  STAGE(0, 0);
  VM_DRAIN();
  __syncthreads();
  int curb = 0;
  for (int t = 0; t < H_DIM / BK; ++t) {
    if (t + 1 < H_DIM / BK) STAGE(curb ^ 1, t + 1);
    COMPUTE(curb);
    VM_DRAIN();
    __syncthreads();
    curb ^= 1;
  }
#pragma unroll
  for (int fm = 0; fm < 2; ++fm)
#pragma unroll
    for (int fn = 0; fn < 2; ++fn)
#pragma unroll
      for (int r = 0; r < 4; ++r) {
        float g = accg[fm][fn][r], u = accu[fm][fn][r];
        float a = g / (1.f + __expf(-g)) * u;
        int row = r0 + wm * 32 + fm * 16 + l4 * 4 + r;
        int col = n0 + wn * 32 + fn * 16 + l15;
        aws[(size_t)row * F_DIM + col] = (__bf16)a;
      }
}

// ---------------- GEMM2: y = a·w2, weighted atomic scatter ----------------
__global__ __launch_bounds__(256) void k_gemm2(const __bf16* __restrict__ aws,
                                               const __bf16* __restrict__ w2p,
                                               const int* __restrict__ ws_i,
                                               float* __restrict__ out) {
  __shared__ __bf16 sm[2][2 * 4096];   // per buf: As | Bs
  __shared__ int s_tok[BM];
  __shared__ float s_w[BM];
  const int p = blockIdx.x;                 // 1280 = 8 XCD * 160
  const int lg = (p & 7) * 160 + (p >> 3);
  const int tile = lg % MAX_TILES;
  const int h0 = (lg / MAX_TILES) * 64;
  if (tile >= ws_i[I_NTILES]) return;
  const int e  = ws_i[I_TILE_E + tile];
  const int r0 = ws_i[I_TILE_R0 + tile];
  const int tid = threadIdx.x, lane = tid & 63, wid = tid >> 6;
  const int wm = wid >> 1, wn = wid & 1;
  const int l15 = lane & 15, l4 = lane >> 4;
  const float* ws_f = (const float*)ws_i;
  if (tid < BM) {
    s_tok[tid] = ws_i[I_ROWTOK + r0 + tid];
    s_w[tid]   = ws_f[I_ROWW + r0 + tid];
  }
  __syncthreads();
  const int rj0 = wid * 16 + (lane >> 3);
  const int rj1 = rj0 + 8;
  const int s8 = (lane & 7) ^ (lane >> 3);
  const __bf16* gA0 = aws + (size_t)(r0 + rj0) * F_DIM + s8 * 8;
  const __bf16* gA1 = aws + (size_t)(r0 + rj1) * F_DIM + s8 * 8;
  // pack8: elem(e,k,h) at e*F*H + ((k>>3)*H + h)*8 + (k&7)
  const __bf16* w2e = w2p + (size_t)e * F_DIM * H_DIM;
  const __bf16* gB0 = w2e + ((size_t)s8 * H_DIM + h0 + rj0) * 8;
  const __bf16* gB1 = w2e + ((size_t)s8 * H_DIM + h0 + rj1) * 8;
  const int c0 = wid * 2 * 512, c1 = c0 + 512;

  auto STAGE = [&](int b, int t) {
    __bf16* As = &sm[b][0];
    __bf16* Bs = &sm[b][4096];
    const size_t ka = (size_t)t * BK;
    const size_t kb = (size_t)t * BK * H_DIM;
    gload16(gA0 + ka, As + c0);
    gload16(gA1 + ka, As + c1);
    gload16(gB0 + kb, Bs + c0);
    gload16(gB1 + kb, Bs + c1);
  };

  f32x4 acc[2][2] = {};
  auto COMPUTE = [&](int b) {
    const __bf16* As = &sm[b][0];
    const __bf16* Bs = &sm[b][4096];
    __builtin_amdgcn_s_setprio(1);
#pragma unroll
    for (int kk = 0; kk < 2; ++kk) {
      const int sx = ((kk * 4 + l4) ^ (lane & 7)) << 3;
      const int ra0 = wm * 32 + l15, ra1 = ra0 + 16;
      const int rb0 = wn * 32 + l15, rb1 = rb0 + 16;
      bf16x8 a0 = *(const bf16x8*)&As[ra0 * 64 + sx];
      bf16x8 a1 = *(const bf16x8*)&As[ra1 * 64 + sx];
      bf16x8 b0 = *(const bf16x8*)&Bs[rb0 * 64 + sx];
      bf16x8 b1 = *(const bf16x8*)&Bs[rb1 * 64 + sx];
      acc[0][0] = MFMA(a0, b0, acc[0][0]);
      acc[0][1] = MFMA(a0, b1, acc[0][1]);
      acc[1][0] = MFMA(a1, b0, acc[1][0]);
      acc[1][1] = MFMA(a1, b1, acc[1][1]);
    }
    __builtin_amdgcn_s_setprio(0);
  };

  STAGE(0, 0);
  VM_DRAIN();
  __syncthreads();
  int curb = 0;
  for (int t = 0; t < F_DIM / BK; ++t) {
    if (t + 1 < F_DIM / BK) STAGE(curb ^ 1, t + 1);
    COMPUTE(curb);
    VM_DRAIN();
    __syncthreads();
    curb ^= 1;
  }
  // exactly 2 atomic adds per output element (K=2): order-independent (a+b exact)
#pragma unroll
  for (int fm = 0; fm < 2; ++fm)
#pragma unroll
    for (int fn = 0; fn < 2; ++fn)
#pragma unroll
      for (int r = 0; r < 4; ++r) {
        int lrow = wm * 32 + fm * 16 + l4 * 4 + r;
        int t = s_tok[lrow];
        if (t >= 0) {
          float v = acc[fm][fn][r] * s_w[lrow];
          atomicAdd(out + (size_t)t * H_DIM + h0 + wn * 32 + fn * 16 + l15, v);
        }
      }
}

extern "C" void kernel_launch(void* const* d_in, const int* in_sizes, int n_in,
                              void* d_out, int out_size, void* d_ws, size_t ws_size,
                              hipStream_t stream) {
  (void)in_sizes; (void)n_in; (void)out_size; (void)ws_size;
  const float* x      = (const float*)d_in[0];
  const float* logits = (const float*)d_in[1];
  const float* w1     = (const float*)d_in[2];
  const float* w3     = (const float*)d_in[3];
  const float* w2     = (const float*)d_in[4];
  float* out = (float*)d_out;
  int* ws_i = (int*)d_ws;
  __bf16* xb  = (__bf16*)((char*)d_ws + B_XB);
  __bf16* aws = (__bf16*)((char*)d_ws + B_AWS);
  __bf16* w1p = (__bf16*)((char*)d_ws + B_W1P);
  __bf16* w3p = (__bf16*)((char*)d_ws + B_W3P);
  __bf16* w2p = (__bf16*)((char*)d_ws + B_W2P);

  hipMemsetAsync(d_out, 0, (size_t)T_TOK * H_DIM * sizeof(float), stream);
  k_route<<<1, 1024, 0, stream>>>(logits, ws_i);
  k_cvt<<<dim3(T_TOK * H_DIM / (256 * 8)), 256, 0, stream>>>(x, xb);
  k_cvtW<<<dim3(2048), 256, 0, stream>>>(w1, w3, w2, w1p, w3p, w2p);
  k_gemm1<<<dim3(MAX_TILES * (F_DIM / 64)), 256, 0, stream>>>(xb, w1p, w3p, ws_i, aws);
  k_gemm2<<<dim3(MAX_TILES * (H_DIM / 64)), 256, 0, stream>>>(aws, w2p, ws_i, out);
}

// Round 12
// 134.528 us; speedup vs baseline: 5.4738x; 1.2509x over previous
//
#include <hip/hip_runtime.h>
#include <cstdint>
#include <cstddef>

// T=1024 tokens, H=2048, F=1024, E=8, K=2
#define T_TOK 1024
#define H_DIM 2048
#define F_DIM 1024
#define E_EXP 8
#define BM 64
#define BK 64
#define MAX_TILES 40
#define ROWCAP 2560

// ---- workspace layout ----
#define I_NTILES 25     // int
#define I_TILE_E 32     // int[48]
#define I_TILE_R0 80    // int[48]
#define I_ROWTOK 4224   // int[2560]
#define I_ROWW   6784   // float[2560]
#define B_XB     37888                          // bf16 x [1024][2048]   (4 MB)
#define B_AWS    (B_XB + T_TOK*H_DIM*2)         // bf16 act [2560][1024] (5 MB)

typedef __bf16 bf16x8 __attribute__((ext_vector_type(8)));
typedef __bf16 bf16x4 __attribute__((ext_vector_type(4)));
typedef float  f32x4  __attribute__((ext_vector_type(4)));

#define MFMA(a,b,c) __builtin_amdgcn_mfma_f32_16x16x32_bf16(a,b,c,0,0,0)

__device__ __forceinline__ void gload16(const void* g, void* l) {
  __builtin_amdgcn_global_load_lds(
      (const __attribute__((address_space(1))) void*)g,
      (__attribute__((address_space(3))) void*)l, 16, 0, 0);
}

// ---------------- deterministic router (r11-verbatim; ws bitwise call-invariant) ----------------
__global__ __launch_bounds__(1024) void k_route(const float* __restrict__ logits,
                                                int* __restrict__ ws_i) {
  __shared__ int wtot[16][E_EXP];
  __shared__ int woff[16][E_EXP];
  __shared__ int offs_s[E_EXP];
  const int t = threadIdx.x;
  const int lane = t & 63, wv = t >> 6;
  float* ws_f = (float*)ws_i;
  float l[E_EXP];
#pragma unroll
  for (int e = 0; e < E_EXP; ++e) l[e] = logits[t * E_EXP + e];
  int b0 = 0; float v0 = l[0];
#pragma unroll
  for (int e = 1; e < E_EXP; ++e) if (l[e] > v0) { v0 = l[e]; b0 = e; }
  int b1 = -1; float v1 = -3.4e38f;
#pragma unroll
  for (int e = 0; e < E_EXP; ++e) if (e != b0 && l[e] > v1) { v1 = l[e]; b1 = e; }
  float w0 = 1.f / (1.f + __expf(v1 - v0));
  float w1 = 1.f - w0;
  unsigned long long inc = (1ull << (8 * b0)) | (1ull << (8 * b1));
  for (int d = 1; d < 64; d <<= 1) {
    unsigned long long n = __shfl_up(inc, (unsigned)d);
    if (lane >= d) inc += n;
  }
  if (lane == 63) {
#pragma unroll
    for (int e = 0; e < E_EXP; ++e) wtot[wv][e] = (int)((inc >> (8 * e)) & 255);
  }
  for (int i = t; i < ROWCAP; i += 1024) {
    ws_i[I_ROWTOK + i] = -1;
    ws_f[I_ROWW + i] = 0.f;
  }
  __syncthreads();
  if (t == 0) {
    int run[E_EXP] = {};
    for (int w = 0; w < 16; ++w)
#pragma unroll
      for (int e = 0; e < E_EXP; ++e) { woff[w][e] = run[e]; run[e] += wtot[w][e]; }
    int off = 0, ntl = 0;
    for (int e = 0; e < E_EXP; ++e) {
      offs_s[e] = off;
      int ntile = (run[e] + BM - 1) / BM;
      for (int i = 0; i < ntile; ++i) {
        ws_i[I_TILE_E + ntl] = e;
        ws_i[I_TILE_R0 + ntl] = off + i * BM;
        ++ntl;
      }
      off += ntile * BM;
    }
    ws_i[I_NTILES] = ntl;
  }
  __syncthreads();
  const int rnk0 = woff[wv][b0] + (int)((inc >> (8 * b0)) & 255) - 1;
  const int rnk1 = woff[wv][b1] + (int)((inc >> (8 * b1)) & 255) - 1;
  const int s0 = offs_s[b0] + rnk0;
  const int s1 = offs_s[b1] + rnk1;
  ws_i[I_ROWTOK + s0] = t;  ws_f[I_ROWW + s0] = w0;
  ws_i[I_ROWTOK + s1] = t;  ws_f[I_ROWW + s1] = w1;
}

// ---------------- x fp32 -> bf16 ----------------
__global__ __launch_bounds__(256) void k_cvt(const float* __restrict__ x,
                                             __bf16* __restrict__ xb) {
  long i = (long)(blockIdx.x * 256 + threadIdx.x) * 8;
  float4 a = *(const float4*)(x + i);
  float4 b = *(const float4*)(x + i + 4);
  bf16x8 v;
  v[0] = (__bf16)a.x; v[1] = (__bf16)a.y; v[2] = (__bf16)a.z; v[3] = (__bf16)a.w;
  v[4] = (__bf16)b.x; v[5] = (__bf16)b.y; v[6] = (__bf16)b.z; v[7] = (__bf16)b.w;
  *(bf16x8*)(xb + i) = v;
}

// ---------------- GEMM1: a = silu(x·w1)*(x·w3), fp32 weights read directly ----------------
// Per K-step (one barrier): issue A-gload(t+1)+B-loads(t+1) right after barrier ->
// COMPUTE(t) covers load latency -> cvt+WRITEB(t+1 -> other buf) -> barrier (drain ~free).
__global__ __launch_bounds__(256) void k_gemm1(const __bf16* __restrict__ xb,
                                               const float* __restrict__ w1,
                                               const float* __restrict__ w3,
                                               const int* __restrict__ ws_i,
                                               __bf16* __restrict__ aws) {
  __shared__ __bf16 sm[2][3 * 4096];   // per buf: As | B1 | B3, 64x64 bf16, octet-swizzled
  __shared__ int s_tok[BM];
  const int p = blockIdx.x;                   // 640 = 8 XCD * 80
  const int lg = (p & 7) * 80 + (p >> 3);
  const int tile = lg % MAX_TILES;
  const int n0 = (lg / MAX_TILES) * 64;
  if (tile >= ws_i[I_NTILES]) return;
  const int e  = ws_i[I_TILE_E + tile];
  const int r0 = ws_i[I_TILE_R0 + tile];
  const int tid = threadIdx.x, lane = tid & 63, wid = tid >> 6;
  const int wm = wid >> 1, wn = wid & 1;
  const int l15 = lane & 15, l4 = lane >> 4;
  if (tid < BM) {
    int tk = ws_i[I_ROWTOK + r0 + tid];
    s_tok[tid] = tk < 0 ? 0 : tk;     // padded rows compute garbage, never scattered
  }
  __syncthreads();
  // A staging (r11-verbatim): gload_lds, source octet pre-swizzled
  const int rj0 = wid * 16 + (lane >> 3);
  const int rj1 = rj0 + 8;
  const int s8 = (lane & 7) ^ (lane >> 3);
  const __bf16* gA0 = xb + (size_t)s_tok[rj0] * H_DIM + s8 * 8;
  const __bf16* gA1 = xb + (size_t)s_tok[rj1] * H_DIM + s8 * 8;
  const int c0 = wid * 2 * 512, c1 = c0 + 512;
  // B staging: thread reads 4 rows (kq..kq+3) x 4 cols (nb..nb+3) fp32, coalesced
  const int nb = (tid & 15) * 4, kq = (tid >> 4) * 4;
  const float* pB1 = w1 + (size_t)e * H_DIM * F_DIM + n0 + nb + (size_t)kq * F_DIM;
  const float* pB3 = w3 + (size_t)e * H_DIM * F_DIM + n0 + nb + (size_t)kq * F_DIM;
  // write byte offsets (half-octet b64, octet-XOR swizzle matching read): per u
  int wboff[4];
#pragma unroll
  for (int u = 0; u < 4; ++u) {
    int n = nb + u;
    wboff[u] = n * 128 + (((kq >> 3) ^ (n & 7)) << 4) + ((kq & 4) << 1);
  }

  f32x4 q1[4], q3[4];
  auto STAGEA = [&](int b, int t) {
    gload16(gA0 + (size_t)t * BK, &sm[b][c0]);
    gload16(gA1 + (size_t)t * BK, &sm[b][c1]);
  };
  auto LOADB = [&](int t) {
    const size_t k0 = (size_t)t * BK * F_DIM;
#pragma unroll
    for (int j = 0; j < 4; ++j) {
      q1[j] = *(const f32x4*)(pB1 + k0 + (size_t)j * F_DIM);
      q3[j] = *(const f32x4*)(pB3 + k0 + (size_t)j * F_DIM);
    }
  };
  auto WRITEB = [&](int b) {
    char* B1 = (char*)&sm[b][4096];
    char* B3 = (char*)&sm[b][8192];
#pragma unroll
    for (int u = 0; u < 4; ++u) {
      bf16x4 v1, v3;
#pragma unroll
      for (int j = 0; j < 4; ++j) { v1[j] = (__bf16)q1[j][u]; v3[j] = (__bf16)q3[j][u]; }
      *(bf16x4*)(B1 + wboff[u]) = v1;
      *(bf16x4*)(B3 + wboff[u]) = v3;
    }
  };

  f32x4 accg[2][2] = {}; f32x4 accu[2][2] = {};
  auto COMPUTE = [&](int b) {
    const __bf16* As = &sm[b][0];
    const __bf16* B1 = &sm[b][4096];
    const __bf16* B3 = &sm[b][8192];
    __builtin_amdgcn_s_setprio(1);
#pragma unroll
    for (int kk = 0; kk < 2; ++kk) {
      const int sx = ((kk * 4 + l4) ^ (lane & 7)) << 3;
      const int ra0 = wm * 32 + l15, ra1 = ra0 + 16;
      const int rb0 = wn * 32 + l15, rb1 = rb0 + 16;
      bf16x8 a0  = *(const bf16x8*)&As[ra0 * 64 + sx];
      bf16x8 a1  = *(const bf16x8*)&As[ra1 * 64 + sx];
      bf16x8 b10 = *(const bf16x8*)&B1[rb0 * 64 + sx];
      bf16x8 b11 = *(const bf16x8*)&B1[rb1 * 64 + sx];
      bf16x8 b30 = *(const bf16x8*)&B3[rb0 * 64 + sx];
      bf16x8 b31 = *(const bf16x8*)&B3[rb1 * 64 + sx];
      accg[0][0] = MFMA(a0, b10, accg[0][0]);
      accg[0][1] = MFMA(a0, b11, accg[0][1]);
      accg[1][0] = MFMA(a1, b10, accg[1][0]);
      accg[1][1] = MFMA(a1, b11, accg[1][1]);
      accu[0][0] = MFMA(a0, b30, accu[0][0]);
      accu[0][1] = MFMA(a0, b31, accu[0][1]);
      accu[1][0] = MFMA(a1, b30, accu[1][0]);
      accu[1][1] = MFMA(a1, b31, accu[1][1]);
    }
    __builtin_amdgcn_s_setprio(0);
  };

  const int NT = H_DIM / BK;   // 32
  // prologue: tile 0 into buf0 (one full-latency stall, once)
  LOADB(0);
  STAGEA(0, 0);
  WRITEB(0);
  __syncthreads();
  int curb = 0;
  for (int t = 0; t < NT; ++t) {
    if (t + 1 < NT) { STAGEA(curb ^ 1, t + 1); LOADB(t + 1); }  // issued early
    COMPUTE(curb);                                              // covers latency
    if (t + 1 < NT) WRITEB(curb ^ 1);                           // consumes loads pre-barrier
    __syncthreads();                                            // drain ~free
    curb ^= 1;
  }
  // epilogue: silu(g)*u -> bf16 (C layout: col=lane&15, row=(lane>>4)*4+reg)
#pragma unroll
  for (int fm = 0; fm < 2; ++fm)
#pragma unroll
    for (int fn = 0; fn < 2; ++fn)
#pragma unroll
      for (int r = 0; r < 4; ++r) {
        float g = accg[fm][fn][r], u = accu[fm][fn][r];
        float a = g / (1.f + __expf(-g)) * u;
        int row = r0 + wm * 32 + fm * 16 + l4 * 4 + r;
        int col = n0 + wn * 32 + fn * 16 + l15;
        aws[(size_t)row * F_DIM + col] = (__bf16)a;
      }
}

// ---------------- GEMM2: y = a·w2 (fp32 direct), weighted atomic scatter ----------------
__global__ __launch_bounds__(256) void k_gemm2(const __bf16* __restrict__ aws,
                                               const float* __restrict__ w2,
                                               const int* __restrict__ ws_i,
                                               float* __restrict__ out) {
  __shared__ __bf16 sm[2][2 * 4096];   // per buf: As | Bs
  __shared__ int s_tok[BM];
  __shared__ float s_w[BM];
  const int p = blockIdx.x;                 // 1280 = 8 XCD * 160
  const int lg = (p & 7) * 160 + (p >> 3);
  const int tile = lg % MAX_TILES;
  const int h0 = (lg / MAX_TILES) * 64;
  if (tile >= ws_i[I_NTILES]) return;
  const int e  = ws_i[I_TILE_E + tile];
  const int r0 = ws_i[I_TILE_R0 + tile];
  const int tid = threadIdx.x, lane = tid & 63, wid = tid >> 6;
  const int wm = wid >> 1, wn = wid & 1;
  const int l15 = lane & 15, l4 = lane >> 4;
  const float* ws_f = (const float*)ws_i;
  if (tid < BM) {
    s_tok[tid] = ws_i[I_ROWTOK + r0 + tid];
    s_w[tid]   = ws_f[I_ROWW + r0 + tid];
  }
  __syncthreads();
  const int rj0 = wid * 16 + (lane >> 3);
  const int rj1 = rj0 + 8;
  const int s8 = (lane & 7) ^ (lane >> 3);
  const __bf16* gA0 = aws + (size_t)(r0 + rj0) * F_DIM + s8 * 8;
  const __bf16* gA1 = aws + (size_t)(r0 + rj1) * F_DIM + s8 * 8;
  const int c0 = wid * 2 * 512, c1 = c0 + 512;
  const int nb = (tid & 15) * 4, kq = (tid >> 4) * 4;
  const float* pB2 = w2 + (size_t)e * F_DIM * H_DIM + h0 + nb + (size_t)kq * H_DIM;
  int wboff[4];
#pragma unroll
  for (int u = 0; u < 4; ++u) {
    int n = nb + u;
    wboff[u] = n * 128 + (((kq >> 3) ^ (n & 7)) << 4) + ((kq & 4) << 1);
  }

  f32x4 q2[4];
  auto STAGEA = [&](int b, int t) {
    gload16(gA0 + (size_t)t * BK, &sm[b][c0]);
    gload16(gA1 + (size_t)t * BK, &sm[b][c1]);
  };
  auto LOADB = [&](int t) {
    const size_t k0 = (size_t)t * BK * H_DIM;
#pragma unroll
    for (int j = 0; j < 4; ++j)
      q2[j] = *(const f32x4*)(pB2 + k0 + (size_t)j * H_DIM);
  };
  auto WRITEB = [&](int b) {
    char* Bs = (char*)&sm[b][4096];
#pragma unroll
    for (int u = 0; u < 4; ++u) {
      bf16x4 v;
#pragma unroll
      for (int j = 0; j < 4; ++j) v[j] = (__bf16)q2[j][u];
      *(bf16x4*)(Bs + wboff[u]) = v;
    }
  };

  f32x4 acc[2][2] = {};
  auto COMPUTE = [&](int b) {
    const __bf16* As = &sm[b][0];
    const __bf16* Bs = &sm[b][4096];
    __builtin_amdgcn_s_setprio(1);
#pragma unroll
    for (int kk = 0; kk < 2; ++kk) {
      const int sx = ((kk * 4 + l4) ^ (lane & 7)) << 3;
      const int ra0 = wm * 32 + l15, ra1 = ra0 + 16;
      const int rb0 = wn * 32 + l15, rb1 = rb0 + 16;
      bf16x8 a0 = *(const bf16x8*)&As[ra0 * 64 + sx];
      bf16x8 a1 = *(const bf16x8*)&As[ra1 * 64 + sx];
      bf16x8 b0 = *(const bf16x8*)&Bs[rb0 * 64 + sx];
      bf16x8 b1 = *(const bf16x8*)&Bs[rb1 * 64 + sx];
      acc[0][0] = MFMA(a0, b0, acc[0][0]);
      acc[0][1] = MFMA(a0, b1, acc[0][1]);
      acc[1][0] = MFMA(a1, b0, acc[1][0]);
      acc[1][1] = MFMA(a1, b1, acc[1][1]);
    }
    __builtin_amdgcn_s_setprio(0);
  };

  const int NT = F_DIM / BK;   // 16
  LOADB(0);
  STAGEA(0, 0);
  WRITEB(0);
  __syncthreads();
  int curb = 0;
  for (int t = 0; t < NT; ++t) {
    if (t + 1 < NT) { STAGEA(curb ^ 1, t + 1); LOADB(t + 1); }
    COMPUTE(curb);
    if (t + 1 < NT) WRITEB(curb ^ 1);
    __syncthreads();
    curb ^= 1;
  }
  // exactly 2 atomic adds per output element (K=2): order-independent (a+b exact)
#pragma unroll
  for (int fm = 0; fm < 2; ++fm)
#pragma unroll
    for (int fn = 0; fn < 2; ++fn)
#pragma unroll
      for (int r = 0; r < 4; ++r) {
        int lrow = wm * 32 + fm * 16 + l4 * 4 + r;
        int t = s_tok[lrow];
        if (t >= 0) {
          float v = acc[fm][fn][r] * s_w[lrow];
          atomicAdd(out + (size_t)t * H_DIM + h0 + wn * 32 + fn * 16 + l15, v);
        }
      }
}

extern "C" void kernel_launch(void* const* d_in, const int* in_sizes, int n_in,
                              void* d_out, int out_size, void* d_ws, size_t ws_size,
                              hipStream_t stream) {
  (void)in_sizes; (void)n_in; (void)out_size; (void)ws_size;
  const float* x      = (const float*)d_in[0];
  const float* logits = (const float*)d_in[1];
  const float* w1     = (const float*)d_in[2];
  const float* w3     = (const float*)d_in[3];
  const float* w2     = (const float*)d_in[4];
  float* out = (float*)d_out;
  int* ws_i = (int*)d_ws;
  __bf16* xb  = (__bf16*)((char*)d_ws + B_XB);
  __bf16* aws = (__bf16*)((char*)d_ws + B_AWS);

  hipMemsetAsync(d_out, 0, (size_t)T_TOK * H_DIM * sizeof(float), stream);
  k_route<<<1, 1024, 0, stream>>>(logits, ws_i);
  k_cvt<<<dim3(T_TOK * H_DIM / (256 * 8)), 256, 0, stream>>>(x, xb);
  k_gemm1<<<dim3(MAX_TILES * (F_DIM / 64)), 256, 0, stream>>>(xb, w1, w3, ws_i, aws);
  k_gemm2<<<dim3(MAX_TILES * (H_DIM / 64)), 256, 0, stream>>>(aws, w2, ws_i, out);
}